// Round 1
// baseline (9620.659 us; speedup 1.0000x reference)
//
#include <hip/hip_runtime.h>
#include <hip/hip_bf16.h>
#include <math.h>
#include <stdint.h>

#define BATCH 128
#define SEQ   512
#define HID   1024

typedef __attribute__((ext_vector_type(8))) short  short8;
typedef __attribute__((ext_vector_type(4))) short  short4v;
typedef __attribute__((ext_vector_type(4))) float  floatx4;
typedef __attribute__((ext_vector_type(8))) __bf16 bf16x8;

__device__ __forceinline__ float bf2f(short s) {
  union { unsigned u; float f; } v;
  v.u = ((unsigned)(unsigned short)s) << 16;
  return v.f;
}
__device__ __forceinline__ short f2bf(float f) {
  union { float f; unsigned u; } v;
  v.f = f;
  unsigned r = 0x7FFFu + ((v.u >> 16) & 1u);   // round-to-nearest-even
  return (short)((v.u + r) >> 16);
}
__device__ __forceinline__ floatx4 MFMA(short8 a, short8 b, floatx4 c) {
  return __builtin_amdgcn_mfma_f32_16x16x32_bf16(
      __builtin_bit_cast(bf16x8, a), __builtin_bit_cast(bf16x8, b), c, 0, 0, 0);
}

// ---------------------------------------------------------------------------
// Transpose + fp32->bf16: out[n][k] = (bf16) in[k][n], both 1024x1024.
// block (32,8), grid (32,32)
// ---------------------------------------------------------------------------
__global__ void k_transpose(const float* __restrict__ in, short* __restrict__ out) {
  __shared__ float tile[32][33];
  const int tx = threadIdx.x, ty = threadIdx.y;
  const int n0 = blockIdx.x << 5, k0 = blockIdx.y << 5;
  #pragma unroll
  for (int i = 0; i < 4; ++i)
    tile[ty + i * 8][tx] = in[(size_t)(k0 + ty + i * 8) * HID + n0 + tx];
  __syncthreads();
  #pragma unroll
  for (int i = 0; i < 4; ++i)
    out[(size_t)(n0 + ty + i * 8) * HID + k0 + tx] = f2bf(tile[tx][ty + i * 8]);
}

// ---------------------------------------------------------------------------
// xp[s][b][h] = bf16( x[b][s][:] @ W_xh + b_h )
// 128x128 tile per WG, 4 waves (2x2), wave = 64x64 (4x4 frags of 16x16x32).
// A staged fp32->bf16 inline; LDS pitch 56 elems (=28 dwords, gcd(28,32)=4 ->
// 8 start banks, 2-way aliasing = free). Epilogue: LDS fp32 transpose -> 8B
// coalesced bf16 stores, two 64-row phases so LDS stays at 33 KB.
// grid (8, 512), block 256
// ---------------------------------------------------------------------------
__global__ __launch_bounds__(256) void k_xp(const float* __restrict__ x,
                                            const short* __restrict__ wxh_t,
                                            const float* __restrict__ b_h,
                                            short* __restrict__ xp) {
  __shared__ __align__(16) char smem[33792];
  short* lds_a = (short*)smem;             // 128*56*2 = 14336
  short* lds_b = (short*)(smem + 14336);   // 14336
  float* lds_e = (float*)smem;             // epilogue: 64*132*4 = 33792

  const int tid  = threadIdx.x;
  const int lane = tid & 63;
  const int wave = tid >> 6;
  const int wm = wave >> 1, wn = wave & 1;
  const int quad = lane >> 4, l15 = lane & 15;
  const int mt = blockIdx.y, nt = blockIdx.x;
  const int b  = mt >> 2;
  const int s0 = (mt & 3) << 7;
  const int n0 = nt << 7;

  floatx4 acc[4][4] = {};
  const float* xbase = x + ((size_t)(b * SEQ + s0)) * HID;

  for (int kt = 0; kt < 32; ++kt) {
    const int k0 = kt << 5;
    #pragma unroll
    for (int i = 0; i < 4; ++i) {              // A: 128 rows x 32 k, fp32->bf16
      int idx = tid + (i << 8);
      int row = idx >> 3, q = idx & 7;
      float4 v = *(const float4*)(xbase + (size_t)row * HID + k0 + (q << 2));
      short4v o = { f2bf(v.x), f2bf(v.y), f2bf(v.z), f2bf(v.w) };
      *(short4v*)(lds_a + row * 56 + (q << 2)) = o;
    }
    #pragma unroll
    for (int i = 0; i < 2; ++i) {              // B: 128 n-rows x 32 k
      int idx = tid + (i << 8);
      int row = idx >> 2, q = idx & 3;
      *(uint4*)(lds_b + row * 56 + (q << 3)) =
          *(const uint4*)(wxh_t + (size_t)(n0 + row) * HID + k0 + (q << 3));
    }
    __syncthreads();
    short8 af[4], bfr[4];
    #pragma unroll
    for (int f = 0; f < 4; ++f)
      af[f] = *(const short8*)(lds_a + (wm * 64 + f * 16 + l15) * 56 + quad * 8);
    #pragma unroll
    for (int f = 0; f < 4; ++f)
      bfr[f] = *(const short8*)(lds_b + (wn * 64 + f * 16 + l15) * 56 + quad * 8);
    #pragma unroll
    for (int mf = 0; mf < 4; ++mf)
      #pragma unroll
      for (int nf = 0; nf < 4; ++nf)
        acc[mf][nf] = MFMA(af[mf], bfr[nf], acc[mf][nf]);
    __syncthreads();
  }

  for (int phase = 0; phase < 2; ++phase) {
    if (wm == phase) {
      #pragma unroll
      for (int mf = 0; mf < 4; ++mf)
        #pragma unroll
        for (int nf = 0; nf < 4; ++nf)
          #pragma unroll
          for (int r = 0; r < 4; ++r)
            lds_e[(mf * 16 + quad * 4 + r) * 132 + wn * 64 + nf * 16 + l15] =
                acc[mf][nf][r];
    }
    __syncthreads();
    #pragma unroll
    for (int i = 0; i < 8; ++i) {
      int idx = tid + (i << 8);
      int row = idx >> 5, c = (idx & 31) << 2;
      float4 v  = *(const float4*)(lds_e + row * 132 + c);
      float4 bh = *(const float4*)(b_h + n0 + c);
      short4v o = { f2bf(v.x + bh.x), f2bf(v.y + bh.y),
                    f2bf(v.z + bh.z), f2bf(v.w + bh.w) };
      int s = s0 + (phase << 6) + row;
      *(short4v*)(xp + ((size_t)s * BATCH + b) * HID + n0 + c) = o;
    }
    __syncthreads();
  }
}

// ---------------------------------------------------------------------------
// Persistent recurrence: 64 WGs (grid = Msplit 2 x Nsplit 32), 256 threads.
// Each WG owns a 64x32 tile of h for all 512 steps; its W_hh^T slice
// (32 cols x 1024 k, bf16 = 64 KB) lives in LDS, XOR-swizzled in 16 B chunks
// so B-frag ds_read_b128 is 2-way (free). A-frags read straight from global
// (L2/LLC). One device-scope barrier per step; h double-buffered in ws.
// ---------------------------------------------------------------------------
__global__ __launch_bounds__(256) void k_rnn(const short* __restrict__ xp,
                                             const short* __restrict__ whh_t,
                                             short* __restrict__ hbuf,
                                             unsigned* __restrict__ ctr) {
  __shared__ __align__(16) short lds_w[32 * 1024];   // 64 KB

  const int tid  = threadIdx.x;
  const int lane = tid & 63;
  const int wave = tid >> 6;
  const int wm = wave >> 1, wn = wave & 1;
  const int quad = lane >> 4, l15 = lane & 15;
  const int wg = blockIdx.x;
  const int m0 = (wg >> 5) << 6;   // 0 or 64 (batch rows)
  const int n0 = (wg & 31) << 5;   // 0..992 (hidden cols)

  #pragma unroll
  for (int i = 0; i < 16; ++i) {   // load W slice once, swizzled
    int idx = tid + (i << 8);
    int row = idx >> 7, q = idx & 127;
    *(uint4*)(lds_w + row * 1024 + ((q ^ (row & 7)) << 3)) =
        *(const uint4*)(whh_t + (size_t)(n0 + row) * HID + (q << 3));
  }
  __syncthreads();

  short* h0 = hbuf;
  short* h1 = hbuf + (size_t)BATCH * HID;

  const int nloc = wn * 16 + l15;           // col within 32-slice
  const int swz  = nloc & 7;
  const short* wrow = lds_w + nloc * 1024;
  const int arow0 = m0 + wm * 32 + l15;
  const int arow1 = arow0 + 16;

  for (int t = 0; t < SEQ; ++t) {
    const short* hr = (t & 1) ? h1 : h0;
    short*       hw = (t & 1) ? h0 : h1;
    floatx4 acc0 = {0.f, 0.f, 0.f, 0.f};
    floatx4 acc1 = {0.f, 0.f, 0.f, 0.f};
    const short* ar0 = hr + (size_t)arow0 * HID;
    const short* ar1 = hr + (size_t)arow1 * HID;
    #pragma unroll 8
    for (int kb = 0; kb < 32; ++kb) {
      int k0 = (kb << 5) + (quad << 3);
      short8 a0 = *(const short8*)(ar0 + k0);
      short8 a1 = *(const short8*)(ar1 + k0);
      int kc = (kb << 2) + quad;
      short8 b0 = *(const short8*)(wrow + ((kc ^ swz) << 3));
      acc0 = MFMA(a0, b0, acc0);
      acc1 = MFMA(a1, b0, acc1);
    }
    #pragma unroll
    for (int f = 0; f < 2; ++f) {            // xp add + tanh + bf16 store
      const floatx4 a = f ? acc1 : acc0;
      int mrow = m0 + wm * 32 + f * 16 + quad * 4;
      int col  = n0 + nloc;
      #pragma unroll
      for (int r = 0; r < 4; ++r) {
        int m = mrow + r;
        float v = bf2f(xp[((size_t)t * BATCH + m) * HID + col]) + a[r];
        hw[(size_t)m * HID + col] = f2bf(tanhf(v));
      }
    }
    if (t != SEQ - 1) {                      // device-wide barrier
      __syncthreads();                       // drains every wave's vmcnt
      if (tid == 0) {
        __threadfence();                     // L2 writeback -> LLC
        __hip_atomic_fetch_add(ctr, 1u, __ATOMIC_RELEASE, __HIP_MEMORY_SCOPE_AGENT);
        unsigned target = 64u * (unsigned)(t + 1);
        while (__hip_atomic_load(ctr, __ATOMIC_ACQUIRE, __HIP_MEMORY_SCOPE_AGENT) < target)
          __builtin_amdgcn_s_sleep(16);
        __threadfence();                     // invalidate L1/L2
      }
      __syncthreads();
    }
  }
}

// ---------------------------------------------------------------------------
// out = h_final @ W_hy + b_y  (fp32 out, 128x1024)
// 64x64 tiles, grid (16,2), block 256, 4 waves (2x2), wave 32x32.
// ---------------------------------------------------------------------------
__global__ __launch_bounds__(256) void k_out(const short* __restrict__ hfin,
                                             const short* __restrict__ why_t,
                                             const float* __restrict__ b_y,
                                             float* __restrict__ out) {
  __shared__ __align__(16) short lds_a[64 * 56];
  __shared__ __align__(16) short lds_b[64 * 56];
  const int tid = threadIdx.x, lane = tid & 63, wave = tid >> 6;
  const int wm = wave >> 1, wn = wave & 1, quad = lane >> 4, l15 = lane & 15;
  const int m0 = blockIdx.y << 6, n0 = blockIdx.x << 6;
  floatx4 acc[2][2] = {};
  for (int kt = 0; kt < 32; ++kt) {
    int k0 = kt << 5;
    int row = tid >> 2, q = tid & 3;
    *(uint4*)(lds_a + row * 56 + (q << 3)) =
        *(const uint4*)(hfin + (size_t)(m0 + row) * HID + k0 + (q << 3));
    *(uint4*)(lds_b + row * 56 + (q << 3)) =
        *(const uint4*)(why_t + (size_t)(n0 + row) * HID + k0 + (q << 3));
    __syncthreads();
    short8 a0 = *(const short8*)(lds_a + (wm * 32 + l15) * 56 + quad * 8);
    short8 a1 = *(const short8*)(lds_a + (wm * 32 + 16 + l15) * 56 + quad * 8);
    short8 b0 = *(const short8*)(lds_b + (wn * 32 + l15) * 56 + quad * 8);
    short8 b1 = *(const short8*)(lds_b + (wn * 32 + 16 + l15) * 56 + quad * 8);
    acc[0][0] = MFMA(a0, b0, acc[0][0]);
    acc[0][1] = MFMA(a0, b1, acc[0][1]);
    acc[1][0] = MFMA(a1, b0, acc[1][0]);
    acc[1][1] = MFMA(a1, b1, acc[1][1]);
    __syncthreads();
  }
  #pragma unroll
  for (int mf = 0; mf < 2; ++mf)
    #pragma unroll
    for (int nf = 0; nf < 2; ++nf)
      #pragma unroll
      for (int r = 0; r < 4; ++r) {
        int row = m0 + wm * 32 + mf * 16 + quad * 4 + r;
        int col = n0 + wn * 32 + nf * 16 + l15;
        out[(size_t)row * HID + col] = acc[mf][nf][r] + b_y[col];
      }
}

// ---------------------------------------------------------------------------
extern "C" void kernel_launch(void* const* d_in, const int* in_sizes, int n_in,
                              void* d_out, int out_size, void* d_ws, size_t ws_size,
                              hipStream_t stream) {
  const float* x   = (const float*)d_in[0];
  const float* wxh = (const float*)d_in[1];
  const float* whh = (const float*)d_in[2];
  const float* b_h = (const float*)d_in[3];
  const float* why = (const float*)d_in[4];
  const float* b_y = (const float*)d_in[5];
  float* out = (float*)d_out;

  char* ws = (char*)d_ws;
  const size_t sz_xp = (size_t)SEQ * BATCH * HID * 2;   // 128 MiB
  const size_t sz_w  = (size_t)HID * HID * 2;           // 2 MiB each
  short*    xp    = (short*)ws;
  short*    wxh_t = (short*)(ws + sz_xp);
  short*    whh_t = (short*)(ws + sz_xp + sz_w);
  short*    why_t = (short*)(ws + sz_xp + 2 * sz_w);
  short*    hbuf  = (short*)(ws + sz_xp + 3 * sz_w);    // 2 x 256 KiB
  unsigned* ctr   = (unsigned*)(ws + sz_xp + 3 * sz_w + (size_t)2 * BATCH * HID * 2);

  // zero h0/h1 + barrier counter (ws is poisoned 0xAA before every launch)
  hipMemsetAsync(hbuf, 0, (size_t)2 * BATCH * HID * 2 + 256, stream);

  dim3 tb(32, 8), tg(32, 32);
  k_transpose<<<tg, tb, 0, stream>>>(wxh, wxh_t);
  k_transpose<<<tg, tb, 0, stream>>>(whh, whh_t);
  k_transpose<<<tg, tb, 0, stream>>>(why, why_t);

  k_xp<<<dim3(8, 512), 256, 0, stream>>>(x, wxh_t, b_h, xp);
  k_rnn<<<64, 256, 0, stream>>>(xp, whh_t, hbuf, ctr);
  k_out<<<dim3(16, 2), 256, 0, stream>>>(hbuf, why_t, b_y, out);
}

// Round 2
// 5184.446 us; speedup vs baseline: 1.8557x; 1.8557x over previous
//
#include <hip/hip_runtime.h>
#include <hip/hip_bf16.h>
#include <math.h>
#include <stdint.h>

#define BATCH 128
#define SEQ   512
#define HID   1024

typedef __attribute__((ext_vector_type(8))) short  short8;
typedef __attribute__((ext_vector_type(4))) short  short4v;
typedef __attribute__((ext_vector_type(4))) float  floatx4;
typedef __attribute__((ext_vector_type(8))) __bf16 bf16x8;

__device__ __forceinline__ float bf2f(unsigned short s) {
  union { unsigned u; float f; } v;
  v.u = ((unsigned)s) << 16;
  return v.f;
}
__device__ __forceinline__ short f2bf(float f) {
  union { float f; unsigned u; } v;
  v.f = f;
  unsigned r = 0x7FFFu + ((v.u >> 16) & 1u);   // round-to-nearest-even
  return (short)((v.u + r) >> 16);
}
__device__ __forceinline__ floatx4 MFMA(short8 a, short8 b, floatx4 c) {
  return __builtin_amdgcn_mfma_f32_16x16x32_bf16(
      __builtin_bit_cast(bf16x8, a), __builtin_bit_cast(bf16x8, b), c, 0, 0, 0);
}

// ---------------------------------------------------------------------------
// Transpose + fp32->bf16: out[n][k] = (bf16) in[k][n], both 1024x1024.
// ---------------------------------------------------------------------------
__global__ void k_transpose(const float* __restrict__ in, short* __restrict__ out) {
  __shared__ float tile[32][33];
  const int tx = threadIdx.x, ty = threadIdx.y;
  const int n0 = blockIdx.x << 5, k0 = blockIdx.y << 5;
  #pragma unroll
  for (int i = 0; i < 4; ++i)
    tile[ty + i * 8][tx] = in[(size_t)(k0 + ty + i * 8) * HID + n0 + tx];
  __syncthreads();
  #pragma unroll
  for (int i = 0; i < 4; ++i)
    out[(size_t)(n0 + ty + i * 8) * HID + k0 + tx] = f2bf(tile[tx][ty + i * 8]);
}

// ---------------------------------------------------------------------------
// xp[s][b][h] = bf16( x[b][s][:] @ W_xh + b_h )   (unchanged from R1)
// ---------------------------------------------------------------------------
__global__ __launch_bounds__(256) void k_xp(const float* __restrict__ x,
                                            const short* __restrict__ wxh_t,
                                            const float* __restrict__ b_h,
                                            short* __restrict__ xp) {
  __shared__ __align__(16) char smem[33792];
  short* lds_a = (short*)smem;
  short* lds_b = (short*)(smem + 14336);
  float* lds_e = (float*)smem;

  const int tid  = threadIdx.x;
  const int lane = tid & 63;
  const int wave = tid >> 6;
  const int wm = wave >> 1, wn = wave & 1;
  const int quad = lane >> 4, l15 = lane & 15;
  const int mt = blockIdx.y, nt = blockIdx.x;
  const int b  = mt >> 2;
  const int s0 = (mt & 3) << 7;
  const int n0 = nt << 7;

  floatx4 acc[4][4] = {};
  const float* xbase = x + ((size_t)(b * SEQ + s0)) * HID;

  for (int kt = 0; kt < 32; ++kt) {
    const int k0 = kt << 5;
    #pragma unroll
    for (int i = 0; i < 4; ++i) {
      int idx = tid + (i << 8);
      int row = idx >> 3, q = idx & 7;
      float4 v = *(const float4*)(xbase + (size_t)row * HID + k0 + (q << 2));
      short4v o = { f2bf(v.x), f2bf(v.y), f2bf(v.z), f2bf(v.w) };
      *(short4v*)(lds_a + row * 56 + (q << 2)) = o;
    }
    #pragma unroll
    for (int i = 0; i < 2; ++i) {
      int idx = tid + (i << 8);
      int row = idx >> 2, q = idx & 3;
      *(uint4*)(lds_b + row * 56 + (q << 3)) =
          *(const uint4*)(wxh_t + (size_t)(n0 + row) * HID + k0 + (q << 3));
    }
    __syncthreads();
    short8 af[4], bfr[4];
    #pragma unroll
    for (int f = 0; f < 4; ++f)
      af[f] = *(const short8*)(lds_a + (wm * 64 + f * 16 + l15) * 56 + quad * 8);
    #pragma unroll
    for (int f = 0; f < 4; ++f)
      bfr[f] = *(const short8*)(lds_b + (wn * 64 + f * 16 + l15) * 56 + quad * 8);
    #pragma unroll
    for (int mf = 0; mf < 4; ++mf)
      #pragma unroll
      for (int nf = 0; nf < 4; ++nf)
        acc[mf][nf] = MFMA(af[mf], bfr[nf], acc[mf][nf]);
    __syncthreads();
  }

  for (int phase = 0; phase < 2; ++phase) {
    if (wm == phase) {
      #pragma unroll
      for (int mf = 0; mf < 4; ++mf)
        #pragma unroll
        for (int nf = 0; nf < 4; ++nf)
          #pragma unroll
          for (int r = 0; r < 4; ++r)
            lds_e[(mf * 16 + quad * 4 + r) * 132 + wn * 64 + nf * 16 + l15] =
                acc[mf][nf][r];
    }
    __syncthreads();
    #pragma unroll
    for (int i = 0; i < 8; ++i) {
      int idx = tid + (i << 8);
      int row = idx >> 5, c = (idx & 31) << 2;
      float4 v  = *(const float4*)(lds_e + row * 132 + c);
      float4 bh = *(const float4*)(b_h + n0 + c);
      short4v o = { f2bf(v.x + bh.x), f2bf(v.y + bh.y),
                    f2bf(v.z + bh.z), f2bf(v.w + bh.w) };
      int s = s0 + (phase << 6) + row;
      *(short4v*)(xp + ((size_t)s * BATCH + b) * HID + n0 + c) = o;
    }
    __syncthreads();
  }
}

// ---------------------------------------------------------------------------
// Persistent recurrence, group-local sync.
// Grid = 128 WGs = 4 m-groups (32 batch rows each) x 32 n-splits (32 cols).
// Sync is ONLY among the 32 WGs of an m-group (batch rows are independent).
// Per-WG flag (64B padded), release store + parallel wave-0 poll, one
// acquire fence (buffer_inv) per step. h stores are write-through agent
// atomics (packed 2xbf16). xp for step t+1 prefetched into registers at the
// top of step t (read-only -> legal across the barrier, hides LLC latency).
// W_hh^T slice (32 cols x 1024 k = 64 KB) persistent in LDS, XOR-swizzled.
// ---------------------------------------------------------------------------
__global__ __launch_bounds__(256) void k_rnn(const short* __restrict__ xp,
                                             const short* __restrict__ whh_t,
                                             short* __restrict__ hbuf,
                                             unsigned* __restrict__ flags) {
  __shared__ __align__(16) short lds_w[32 * 1024];   // 64 KB

  const int tid  = threadIdx.x;
  const int lane = tid & 63;
  const int wave = tid >> 6;
  const int wm = wave >> 1, wn = wave & 1;
  const int quad = lane >> 4, l15 = lane & 15;
  const int wg  = blockIdx.x;
  const int grp = wg >> 5;          // m-group 0..3
  const int nsl = wg & 31;          // n-slice 0..31
  const int m0  = grp << 5;         // batch-row base (32 rows)
  const int n0  = nsl << 5;         // hidden-col base (32 cols)

  #pragma unroll
  for (int i = 0; i < 16; ++i) {    // load W slice once, swizzled
    int idx = tid + (i << 8);
    int row = idx >> 7, q = idx & 127;
    *(uint4*)(lds_w + row * 1024 + ((q ^ (row & 7)) << 3)) =
        *(const uint4*)(whh_t + (size_t)(n0 + row) * HID + (q << 3));
  }
  __syncthreads();

  short* h0 = hbuf;
  short* h1 = hbuf + (size_t)BATCH * HID;

  const int nloc = wn * 16 + l15;          // col within 32-slice
  const int col  = n0 + nloc;              // absolute hidden col
  const int swz  = nloc & 7;
  const short* wrow = lds_w + nloc * 1024;
  const int arow = m0 + wm * 16 + l15;     // A-frag row (16 rows per wave)
  const int erow = m0 + wm * 16 + quad * 4;// epilogue row base

  // prefetch xp for t=0
  unsigned short xv[4], xn[4];
  #pragma unroll
  for (int r = 0; r < 4; ++r)
    xv[r] = *(const unsigned short*)(xp + ((size_t)0 * BATCH + erow + r) * HID + col);

  for (int t = 0; t < SEQ; ++t) {
    // prefetch xp for t+1 (overlaps k-loop + barrier)
    if (t + 1 < SEQ) {
      #pragma unroll
      for (int r = 0; r < 4; ++r)
        xn[r] = *(const unsigned short*)(xp + ((size_t)(t + 1) * BATCH + erow + r) * HID + col);
    }

    const short* hr = (t & 1) ? h1 : h0;
    short*       hw = (t & 1) ? h0 : h1;
    floatx4 acc = {0.f, 0.f, 0.f, 0.f};
    const short* ar = hr + (size_t)arow * HID;
    #pragma unroll 8
    for (int kb = 0; kb < 32; ++kb) {
      short8 a = *(const short8*)(ar + (kb << 5) + (quad << 3));
      int kc = (kb << 2) + quad;
      short8 b = *(const short8*)(wrow + ((kc ^ swz) << 3));
      acc = MFMA(a, b, acc);
    }

    // epilogue: xp add + tanh + packed write-through store
    #pragma unroll
    for (int r = 0; r < 4; ++r) {
      float v = tanhf(bf2f(xv[r]) + acc[r]);
      unsigned mine = (unsigned short)f2bf(v);
      unsigned partner = (unsigned)__shfl_xor((int)mine, 1);
      if ((l15 & 1) == 0) {
        unsigned packed = mine | (partner << 16);
        __hip_atomic_store((unsigned*)(hw + (size_t)(erow + r) * HID + col),
                           packed, __ATOMIC_RELAXED, __HIP_MEMORY_SCOPE_AGENT);
      }
    }

    if (t != SEQ - 1) {
      __syncthreads();                      // all stores issued + drained
      if (tid == 0)
        __hip_atomic_store(flags + (size_t)wg * 16, (unsigned)(t + 1),
                           __ATOMIC_RELEASE, __HIP_MEMORY_SCOPE_AGENT);
      if (wave == 0) {                      // poll group's 32 flags in parallel
        const unsigned tgt = (unsigned)(t + 1);
        const unsigned* fp = flags + (size_t)(grp * 32 + (lane & 31)) * 16;
        for (;;) {
          unsigned v = (lane < 32)
              ? __hip_atomic_load(fp, __ATOMIC_RELAXED, __HIP_MEMORY_SCOPE_AGENT)
              : tgt;
          if (__ballot(v >= tgt) == ~0ull) break;
          __builtin_amdgcn_s_sleep(1);
        }
      }
      __syncthreads();
      __builtin_amdgcn_fence(__ATOMIC_ACQUIRE, "agent");  // one buffer_inv
      #pragma unroll
      for (int r = 0; r < 4; ++r) xv[r] = xn[r];
    }
  }
}

// ---------------------------------------------------------------------------
// out = h_final @ W_hy + b_y  (fp32 out, 128x1024)   (unchanged from R1)
// ---------------------------------------------------------------------------
__global__ __launch_bounds__(256) void k_out(const short* __restrict__ hfin,
                                             const short* __restrict__ why_t,
                                             const float* __restrict__ b_y,
                                             float* __restrict__ out) {
  __shared__ __align__(16) short lds_a[64 * 56];
  __shared__ __align__(16) short lds_b[64 * 56];
  const int tid = threadIdx.x, lane = tid & 63, wave = tid >> 6;
  const int wm = wave >> 1, wn = wave & 1, quad = lane >> 4, l15 = lane & 15;
  const int m0 = blockIdx.y << 6, n0 = blockIdx.x << 6;
  floatx4 acc[2][2] = {};
  for (int kt = 0; kt < 32; ++kt) {
    int k0 = kt << 5;
    int row = tid >> 2, q = tid & 3;
    *(uint4*)(lds_a + row * 56 + (q << 3)) =
        *(const uint4*)(hfin + (size_t)(m0 + row) * HID + k0 + (q << 3));
    *(uint4*)(lds_b + row * 56 + (q << 3)) =
        *(const uint4*)(why_t + (size_t)(n0 + row) * HID + k0 + (q << 3));
    __syncthreads();
    short8 a0 = *(const short8*)(lds_a + (wm * 32 + l15) * 56 + quad * 8);
    short8 a1 = *(const short8*)(lds_a + (wm * 32 + 16 + l15) * 56 + quad * 8);
    short8 b0 = *(const short8*)(lds_b + (wn * 32 + l15) * 56 + quad * 8);
    short8 b1 = *(const short8*)(lds_b + (wn * 32 + 16 + l15) * 56 + quad * 8);
    acc[0][0] = MFMA(a0, b0, acc[0][0]);
    acc[0][1] = MFMA(a0, b1, acc[0][1]);
    acc[1][0] = MFMA(a1, b0, acc[1][0]);
    acc[1][1] = MFMA(a1, b1, acc[1][1]);
    __syncthreads();
  }
  #pragma unroll
  for (int mf = 0; mf < 2; ++mf)
    #pragma unroll
    for (int nf = 0; nf < 2; ++nf)
      #pragma unroll
      for (int r = 0; r < 4; ++r) {
        int row = m0 + wm * 32 + mf * 16 + quad * 4 + r;
        int col = n0 + wn * 32 + nf * 16 + l15;
        out[(size_t)row * HID + col] = acc[mf][nf][r] + b_y[col];
      }
}

// ---------------------------------------------------------------------------
extern "C" void kernel_launch(void* const* d_in, const int* in_sizes, int n_in,
                              void* d_out, int out_size, void* d_ws, size_t ws_size,
                              hipStream_t stream) {
  const float* x   = (const float*)d_in[0];
  const float* wxh = (const float*)d_in[1];
  const float* whh = (const float*)d_in[2];
  const float* b_h = (const float*)d_in[3];
  const float* why = (const float*)d_in[4];
  const float* b_y = (const float*)d_in[5];
  float* out = (float*)d_out;

  char* ws = (char*)d_ws;
  const size_t sz_xp = (size_t)SEQ * BATCH * HID * 2;   // 128 MiB
  const size_t sz_w  = (size_t)HID * HID * 2;           // 2 MiB each
  const size_t sz_h  = (size_t)2 * BATCH * HID * 2;     // 512 KiB
  short*    xp    = (short*)ws;
  short*    wxh_t = (short*)(ws + sz_xp);
  short*    whh_t = (short*)(ws + sz_xp + sz_w);
  short*    why_t = (short*)(ws + sz_xp + 2 * sz_w);
  short*    hbuf  = (short*)(ws + sz_xp + 3 * sz_w);
  unsigned* flags = (unsigned*)(ws + sz_xp + 3 * sz_w + sz_h);  // 128 x 64 B

  // zero h0/h1 + flags (ws is poisoned 0xAA before every launch)
  hipMemsetAsync(hbuf, 0, sz_h + 128 * 64, stream);

  dim3 tb(32, 8), tg(32, 32);
  k_transpose<<<tg, tb, 0, stream>>>(wxh, wxh_t);
  k_transpose<<<tg, tb, 0, stream>>>(whh, whh_t);
  k_transpose<<<tg, tb, 0, stream>>>(why, why_t);

  k_xp<<<dim3(8, 512), 256, 0, stream>>>(x, wxh_t, b_h, xp);
  k_rnn<<<128, 256, 0, stream>>>(xp, whh_t, hbuf, flags);
  k_out<<<dim3(16, 2), 256, 0, stream>>>(hbuf, why_t, b_y, out);
}

// Round 3
// 4116.844 us; speedup vs baseline: 2.3369x; 1.2593x over previous
//
#include <hip/hip_runtime.h>
#include <hip/hip_bf16.h>
#include <math.h>
#include <stdint.h>

#define BATCH 128
#define SEQ   512
#define HID   1024

typedef __attribute__((ext_vector_type(8))) short  short8;
typedef __attribute__((ext_vector_type(4))) short  short4v;
typedef __attribute__((ext_vector_type(4))) float  floatx4;
typedef __attribute__((ext_vector_type(8))) __bf16 bf16x8;
typedef unsigned long long ull;

__device__ __forceinline__ float bf2f(unsigned short s) {
  union { unsigned u; float f; } v;
  v.u = ((unsigned)s) << 16;
  return v.f;
}
__device__ __forceinline__ short f2bf(float f) {
  union { float f; unsigned u; } v;
  v.f = f;
  unsigned r = 0x7FFFu + ((v.u >> 16) & 1u);   // round-to-nearest-even
  return (short)((v.u + r) >> 16);
}
__device__ __forceinline__ floatx4 MFMA(short8 a, short8 b, floatx4 c) {
  return __builtin_amdgcn_mfma_f32_16x16x32_bf16(
      __builtin_bit_cast(bf16x8, a), __builtin_bit_cast(bf16x8, b), c, 0, 0, 0);
}

// ---------------------------------------------------------------------------
// Transpose + fp32->bf16: out[n][k] = (bf16) in[k][n], both 1024x1024.
// ---------------------------------------------------------------------------
__global__ void k_transpose(const float* __restrict__ in, short* __restrict__ out) {
  __shared__ float tile[32][33];
  const int tx = threadIdx.x, ty = threadIdx.y;
  const int n0 = blockIdx.x << 5, k0 = blockIdx.y << 5;
  #pragma unroll
  for (int i = 0; i < 4; ++i)
    tile[ty + i * 8][tx] = in[(size_t)(k0 + ty + i * 8) * HID + n0 + tx];
  __syncthreads();
  #pragma unroll
  for (int i = 0; i < 4; ++i)
    out[(size_t)(n0 + ty + i * 8) * HID + k0 + tx] = f2bf(tile[tx][ty + i * 8]);
}

// ---------------------------------------------------------------------------
// xp[s][b][h] = bf16( x[b][s][:] @ W_xh + b_h )   (unchanged)
// ---------------------------------------------------------------------------
__global__ __launch_bounds__(256) void k_xp(const float* __restrict__ x,
                                            const short* __restrict__ wxh_t,
                                            const float* __restrict__ b_h,
                                            short* __restrict__ xp) {
  __shared__ __align__(16) char smem[33792];
  short* lds_a = (short*)smem;
  short* lds_b = (short*)(smem + 14336);
  float* lds_e = (float*)smem;

  const int tid  = threadIdx.x;
  const int lane = tid & 63;
  const int wave = tid >> 6;
  const int wm = wave >> 1, wn = wave & 1;
  const int quad = lane >> 4, l15 = lane & 15;
  const int mt = blockIdx.y, nt = blockIdx.x;
  const int b  = mt >> 2;
  const int s0 = (mt & 3) << 7;
  const int n0 = nt << 7;

  floatx4 acc[4][4] = {};
  const float* xbase = x + ((size_t)(b * SEQ + s0)) * HID;

  for (int kt = 0; kt < 32; ++kt) {
    const int k0 = kt << 5;
    #pragma unroll
    for (int i = 0; i < 4; ++i) {
      int idx = tid + (i << 8);
      int row = idx >> 3, q = idx & 7;
      float4 v = *(const float4*)(xbase + (size_t)row * HID + k0 + (q << 2));
      short4v o = { f2bf(v.x), f2bf(v.y), f2bf(v.z), f2bf(v.w) };
      *(short4v*)(lds_a + row * 56 + (q << 2)) = o;
    }
    #pragma unroll
    for (int i = 0; i < 2; ++i) {
      int idx = tid + (i << 8);
      int row = idx >> 2, q = idx & 3;
      *(uint4*)(lds_b + row * 56 + (q << 3)) =
          *(const uint4*)(wxh_t + (size_t)(n0 + row) * HID + k0 + (q << 3));
    }
    __syncthreads();
    short8 af[4], bfr[4];
    #pragma unroll
    for (int f = 0; f < 4; ++f)
      af[f] = *(const short8*)(lds_a + (wm * 64 + f * 16 + l15) * 56 + quad * 8);
    #pragma unroll
    for (int f = 0; f < 4; ++f)
      bfr[f] = *(const short8*)(lds_b + (wn * 64 + f * 16 + l15) * 56 + quad * 8);
    #pragma unroll
    for (int mf = 0; mf < 4; ++mf)
      #pragma unroll
      for (int nf = 0; nf < 4; ++nf)
        acc[mf][nf] = MFMA(af[mf], bfr[nf], acc[mf][nf]);
    __syncthreads();
  }

  for (int phase = 0; phase < 2; ++phase) {
    if (wm == phase) {
      #pragma unroll
      for (int mf = 0; mf < 4; ++mf)
        #pragma unroll
        for (int nf = 0; nf < 4; ++nf)
          #pragma unroll
          for (int r = 0; r < 4; ++r)
            lds_e[(mf * 16 + quad * 4 + r) * 132 + wn * 64 + nf * 16 + l15] =
                acc[mf][nf][r];
    }
    __syncthreads();
    #pragma unroll
    for (int i = 0; i < 8; ++i) {
      int idx = tid + (i << 8);
      int row = idx >> 5, c = (idx & 31) << 2;
      float4 v  = *(const float4*)(lds_e + row * 132 + c);
      float4 bh = *(const float4*)(b_h + n0 + c);
      short4v o = { f2bf(v.x + bh.x), f2bf(v.y + bh.y),
                    f2bf(v.z + bh.z), f2bf(v.w + bh.w) };
      int s = s0 + (phase << 6) + row;
      *(short4v*)(xp + ((size_t)s * BATCH + b) * HID + n0 + c) = o;
    }
    __syncthreads();
  }
}

// ---------------------------------------------------------------------------
// Persistent recurrence, fence-free coherent protocol.
// Grid = 128 WGs = 4 m-groups (32 batch rows) x 32 n-slices (32 cols).
// All h + flag traffic uses agent-scope RELAXED atomics -> plain
// global_load/store sc0 sc1: bypasses L1/L2, coherent at LLC, NO wbl2/inv
// ever (the R2 killer). Per step: cooperative coherent stage-in of the
// group's 32x1024 h slice into LDS (64 KB, XOR-swizzled), k-loop entirely
// from LDS (ds_read_b128, 2-way = free), 4 split accumulators (breaks the
// 32-long dependent MFMA chain), tanh + packed coherent store, barrier,
// relaxed flag store (ordering via the barrier's vmcnt(0) drain), parallel
// wave-0 poll of the group's 32 flags. W slice (64 KB) persistent in LDS.
// LDS total 128 KB <= 160 KB, 1 WG/CU.
// ---------------------------------------------------------------------------
__global__ __launch_bounds__(256) void k_rnn(const short* __restrict__ xp,
                                             const short* __restrict__ whh_t,
                                             short* __restrict__ hbuf,
                                             unsigned* __restrict__ flags) {
  __shared__ __align__(16) short lds_w[32 * 1024];   // 64 KB W_hh^T slice
  __shared__ __align__(16) short lds_h[32 * 1024];   // 64 KB h(t) stage

  const int tid  = threadIdx.x;
  const int lane = tid & 63;
  const int wave = tid >> 6;
  const int wm = wave >> 1, wn = wave & 1;
  const int quad = lane >> 4, l15 = lane & 15;
  const int wg  = blockIdx.x;
  const int grp = wg >> 5;          // m-group 0..3
  const int nsl = wg & 31;          // n-slice 0..31
  const int m0  = grp << 5;         // batch-row base (32 rows)
  const int n0  = nsl << 5;         // hidden-col base (32 cols)

  #pragma unroll
  for (int i = 0; i < 16; ++i) {    // load W slice once, swizzled
    int idx = tid + (i << 8);
    int row = idx >> 7, q = idx & 127;
    *(uint4*)(lds_w + row * 1024 + ((q ^ (row & 7)) << 3)) =
        *(const uint4*)(whh_t + (size_t)(n0 + row) * HID + (q << 3));
  }

  short* h0 = hbuf;
  short* h1 = hbuf + (size_t)BATCH * HID;

  const int nloc = wn * 16 + l15;           // col within 32-slice
  const int col  = n0 + nloc;               // absolute hidden col
  const int swz  = nloc & 7;
  const short* wrow = lds_w + nloc * 1024;
  const int lrow = wm * 16 + l15;           // local A row 0..31
  const int aswz = lrow & 7;
  const short* hrow = lds_h + lrow * 1024;
  const int erow = m0 + wm * 16 + quad * 4; // epilogue row base

  // stage-in addressing: 16 iters x 256 threads = 4096 16-B chunks
  const int si_row = tid >> 3;              // 0..31 (row stride 8 per iter? no:)
  // (computed per-iteration below instead)

  // prefetch xp for t=0
  unsigned short xv[4], xn[4];
  #pragma unroll
  for (int r = 0; r < 4; ++r)
    xv[r] = *(const unsigned short*)(xp + ((size_t)(erow + r)) * HID + col);

  __syncthreads();                          // W staged

  for (int t = 0; t < SEQ; ++t) {
    // ---- wait for h(t) (skip at t=0: memset zeros, already coherent) ----
    if (t > 0) {
      if (wave == 0) {
        const unsigned tgt = (unsigned)t;
        const unsigned* fp = flags + (size_t)(grp * 32 + (lane & 31)) * 16;
        for (;;) {
          unsigned v = (lane < 32)
              ? __hip_atomic_load(fp, __ATOMIC_RELAXED, __HIP_MEMORY_SCOPE_AGENT)
              : tgt;
          if (__ballot(v >= tgt) == ~0ull) break;
          __builtin_amdgcn_s_sleep(1);
        }
      }
      __syncthreads();                      // everyone sees poll success
    }

    // ---- coherent stage-in of h(t) slice (32 rows x 1024) into LDS ----
    const short* hr = (t & 1) ? h1 : h0;
    #pragma unroll
    for (int i = 0; i < 16; ++i) {
      int idx = tid + (i << 8);             // 16-B chunk id
      int row = idx >> 7, q = idx & 127;
      const ull* src = (const ull*)(hr + (size_t)(m0 + row) * HID + (q << 3));
      ull lo = __hip_atomic_load(src,     __ATOMIC_RELAXED, __HIP_MEMORY_SCOPE_AGENT);
      ull hi = __hip_atomic_load(src + 1, __ATOMIC_RELAXED, __HIP_MEMORY_SCOPE_AGENT);
      short* dst = lds_h + row * 1024 + ((q ^ (row & 7)) << 3);
      *(ull*)dst = lo;
      *((ull*)dst + 1) = hi;
    }

    // prefetch xp for t+1 (cached loads; L2 is never invalidated now)
    if (t + 1 < SEQ) {
      #pragma unroll
      for (int r = 0; r < 4; ++r)
        xn[r] = *(const unsigned short*)(xp + ((size_t)(t + 1) * BATCH + erow + r) * HID + col);
    }

    __syncthreads();                        // h(t) staged

    // ---- k-loop: pure LDS, 4 split accumulator chains ----
    floatx4 ac0 = {0.f,0.f,0.f,0.f}, ac1 = {0.f,0.f,0.f,0.f};
    floatx4 ac2 = {0.f,0.f,0.f,0.f}, ac3 = {0.f,0.f,0.f,0.f};
    #pragma unroll
    for (int kb = 0; kb < 32; kb += 4) {
      #pragma unroll
      for (int j = 0; j < 4; ++j) {
        int kc = ((kb + j) << 2) + quad;    // 16-B chunk index 0..127
        short8 a = *(const short8*)(hrow + ((kc ^ aswz) << 3));
        short8 b = *(const short8*)(wrow + ((kc ^ swz) << 3));
        floatx4& ac = j == 0 ? ac0 : j == 1 ? ac1 : j == 2 ? ac2 : ac3;
        ac = MFMA(a, b, ac);
      }
    }
    floatx4 acc = (ac0 + ac1) + (ac2 + ac3);

    // ---- epilogue: xp add + tanh + packed coherent store of h(t+1) ----
    short* hw = (t & 1) ? h0 : h1;
    #pragma unroll
    for (int r = 0; r < 4; ++r) {
      float v = tanhf(bf2f(xv[r]) + acc[r]);
      unsigned mine = (unsigned short)f2bf(v);
      unsigned partner = (unsigned)__shfl_xor((int)mine, 1);
      if ((l15 & 1) == 0) {
        unsigned packed = mine | (partner << 16);
        __hip_atomic_store((unsigned*)(hw + (size_t)(erow + r) * HID + col),
                           packed, __ATOMIC_RELAXED, __HIP_MEMORY_SCOPE_AGENT);
      }
    }
    #pragma unroll
    for (int r = 0; r < 4; ++r) xv[r] = xn[r];

    if (t != SEQ - 1) {
      // barrier: every wave drains vmcnt(0) before s_barrier -> all h(t+1)
      // stores are ack'd at the coherence point; also guards lds_h reuse.
      __syncthreads();
      if (tid == 0)                          // relaxed: no wbl2
        __hip_atomic_store(flags + (size_t)wg * 16, (unsigned)(t + 1),
                           __ATOMIC_RELAXED, __HIP_MEMORY_SCOPE_AGENT);
    }
  }
}

// ---------------------------------------------------------------------------
// out = h_final @ W_hy + b_y  (fp32 out, 128x1024)   (unchanged)
// ---------------------------------------------------------------------------
__global__ __launch_bounds__(256) void k_out(const short* __restrict__ hfin,
                                             const short* __restrict__ why_t,
                                             const float* __restrict__ b_y,
                                             float* __restrict__ out) {
  __shared__ __align__(16) short lds_a[64 * 56];
  __shared__ __align__(16) short lds_b[64 * 56];
  const int tid = threadIdx.x, lane = tid & 63, wave = tid >> 6;
  const int wm = wave >> 1, wn = wave & 1, quad = lane >> 4, l15 = lane & 15;
  const int m0 = blockIdx.y << 6, n0 = blockIdx.x << 6;
  floatx4 acc[2][2] = {};
  for (int kt = 0; kt < 32; ++kt) {
    int k0 = kt << 5;
    int row = tid >> 2, q = tid & 3;
    *(uint4*)(lds_a + row * 56 + (q << 3)) =
        *(const uint4*)(hfin + (size_t)(m0 + row) * HID + k0 + (q << 3));
    *(uint4*)(lds_b + row * 56 + (q << 3)) =
        *(const uint4*)(why_t + (size_t)(n0 + row) * HID + k0 + (q << 3));
    __syncthreads();
    short8 a0 = *(const short8*)(lds_a + (wm * 32 + l15) * 56 + quad * 8);
    short8 a1 = *(const short8*)(lds_a + (wm * 32 + 16 + l15) * 56 + quad * 8);
    short8 b0 = *(const short8*)(lds_b + (wn * 32 + l15) * 56 + quad * 8);
    short8 b1 = *(const short8*)(lds_b + (wn * 32 + 16 + l15) * 56 + quad * 8);
    acc[0][0] = MFMA(a0, b0, acc[0][0]);
    acc[0][1] = MFMA(a0, b1, acc[0][1]);
    acc[1][0] = MFMA(a1, b0, acc[1][0]);
    acc[1][1] = MFMA(a1, b1, acc[1][1]);
    __syncthreads();
  }
  #pragma unroll
  for (int mf = 0; mf < 2; ++mf)
    #pragma unroll
    for (int nf = 0; nf < 2; ++nf)
      #pragma unroll
      for (int r = 0; r < 4; ++r) {
        int row = m0 + wm * 32 + mf * 16 + quad * 4 + r;
        int col = n0 + wn * 32 + nf * 16 + l15;
        out[(size_t)row * HID + col] = acc[mf][nf][r] + b_y[col];
      }
}

// ---------------------------------------------------------------------------
extern "C" void kernel_launch(void* const* d_in, const int* in_sizes, int n_in,
                              void* d_out, int out_size, void* d_ws, size_t ws_size,
                              hipStream_t stream) {
  const float* x   = (const float*)d_in[0];
  const float* wxh = (const float*)d_in[1];
  const float* whh = (const float*)d_in[2];
  const float* b_h = (const float*)d_in[3];
  const float* why = (const float*)d_in[4];
  const float* b_y = (const float*)d_in[5];
  float* out = (float*)d_out;

  char* ws = (char*)d_ws;
  const size_t sz_xp = (size_t)SEQ * BATCH * HID * 2;   // 128 MiB
  const size_t sz_w  = (size_t)HID * HID * 2;           // 2 MiB each
  const size_t sz_h  = (size_t)2 * BATCH * HID * 2;     // 512 KiB
  short*    xp    = (short*)ws;
  short*    wxh_t = (short*)(ws + sz_xp);
  short*    whh_t = (short*)(ws + sz_xp + sz_w);
  short*    why_t = (short*)(ws + sz_xp + 2 * sz_w);
  short*    hbuf  = (short*)(ws + sz_xp + 3 * sz_w);
  unsigned* flags = (unsigned*)(ws + sz_xp + 3 * sz_w + sz_h);  // 128 x 64 B

  // zero h0/h1 + flags (ws is poisoned 0xAA before every launch)
  hipMemsetAsync(hbuf, 0, sz_h + 128 * 64, stream);

  dim3 tb(32, 8), tg(32, 32);
  k_transpose<<<tg, tb, 0, stream>>>(wxh, wxh_t);
  k_transpose<<<tg, tb, 0, stream>>>(whh, whh_t);
  k_transpose<<<tg, tb, 0, stream>>>(why, why_t);

  k_xp<<<dim3(8, 512), 256, 0, stream>>>(x, wxh_t, b_h, xp);
  k_rnn<<<128, 256, 0, stream>>>(xp, whh_t, hbuf, flags);
  k_out<<<dim3(16, 2), 256, 0, stream>>>(hbuf, why_t, b_y, out);
}